// Round 12
// baseline (37491.992 us; speedup 1.0000x reference)
//
#include <hip/hip_runtime.h>
#include <math.h>

#define DD 64
#define NSWEEP 8

__device__ __forceinline__ float rdlane(float v, int l) {
    return __int_as_float(__builtin_amdgcn_readlane(__float_as_int(v), l));
}
__device__ __forceinline__ float bperm(int paddr, float v) {
    return __int_as_float(__builtin_amdgcn_ds_bpermute(paddr, __float_as_int(v)));
}

// ---------------- Kernel 1: Cholesky + one-sided Jacobi sweeps ----------------
// 64-thread blocks, ZERO LDS. No asm pin (round-11 lesson: pinning oth live
// makes the allocator spill to scratch -> 520MB extra HBM traffic; the no-pin
// codegen is VGPR=80, scratch-free, with bpermute remat). launch_bounds(64,5)
// caps VGPR at 102 (natural 80-84 fits) -> up to 20 waves/CU for latency hiding.
__global__ __launch_bounds__(64, 5)
void logeig_sweeps_kernel(const float* __restrict__ X, float* __restrict__ Wout, int nb) {
    const int b = blockIdx.x;
    if (b >= nb) return;
    const int lane = threadIdx.x & 63;
    const float* Xb = X + (size_t)b * DD * DD;

    // Symmetrize directly from global: coalesced column + row (L1/L2-served).
    float w[DD];
    #pragma unroll
    for (int e = 0; e < DD; ++e)
        w[e] = 0.5f * (Xb[e * DD + lane] + Xb[lane * DD + e]);

    // ---- In-wave right-looking Cholesky: lane j ends owning column j of L ----
    #pragma unroll
    for (int k = 0; k < DD; ++k) {
        const float pivot = rdlane(w[k], k);          // A'[k][k] > 0 (SPD)
        const float rinv  = 1.0f / sqrtf(pivot);
        const float ljk   = w[k] * rinv;              // L[lane][k], valid lane >= k
        const bool  gtk   = (lane > k);
        const bool  eqk   = (lane == k);
        #pragma unroll
        for (int e = k; e < DD; ++e) {
            const float lek = rdlane(w[e], k) * rinv; // L[e][k] (uniform)
            const float upd = fmaf(-lek, ljk, w[e]);
            w[e] = eqk ? lek : (gtk ? upd : w[e]);
        }
    }
    #pragma unroll
    for (int e = 0; e < DD - 1; ++e)
        w[e] = (e < lane) ? 0.0f : w[e];

    // Initial column norm^2 (maintained incrementally)
    float nown;
    {
        float n0 = 0.f, n1 = 0.f;
        #pragma unroll
        for (int e = 0; e < DD; e += 2) {
            n0 = fmaf(w[e],     w[e],     n0);
            n1 = fmaf(w[e + 1], w[e + 1], n1);
        }
        nown = n0 + n1;
    }

    const int lane4 = lane << 2;

    for (int sw = 0; sw < NSWEEP; ++sw) {
        bool sweep_rotated = false;
        for (int m = 1; m < DD; ++m) {
            const int paddr = lane4 ^ (m << 2);   // partner*4 (XOR pairing)

            float oth[DD];
            #pragma unroll
            for (int e = 0; e < DD; ++e) oth[e] = bperm(paddr, w[e]);

            // d = w . oth (identical summation order both lanes -> bitwise-equal)
            float d0 = 0.f, d1 = 0.f, d2 = 0.f, d3 = 0.f;
            #pragma unroll
            for (int e = 0; e < DD; e += 4) {
                d0 = fmaf(w[e],     oth[e],     d0);
                d1 = fmaf(w[e + 1], oth[e + 1], d1);
                d2 = fmaf(w[e + 2], oth[e + 2], d2);
                d3 = fmaf(w[e + 3], oth[e + 3], d3);
            }
            const float d    = (d0 + d1) + (d2 + d3);
            const float noth = bperm(paddr, nown);

            // Relative threshold 1e-5 (absmax-neutral, rounds 9-11):
            // late sweeps become all-skip so the early exit fires.
            const bool dorot = (d * d > 1e-10f * nown * noth);
            if (__any(dorot)) {
                sweep_rotated = true;
                const bool  islo = (paddr > lane4);   // low lane plays p
                const float app  = islo ? nown : noth;
                const float aqq  = islo ? noth : nown;
                float tau = (aqq - app) * 0.5f / d;
                float t   = 1.0f / (fabsf(tau) + sqrtf(fmaf(tau, tau, 1.0f)));
                t = copysignf(t, tau);
                float c = 1.0f / sqrtf(fmaf(t, t, 1.0f));
                float s = t * c;
                float tsgn = islo ? -t : t;           // nown' = nown -+ t*d
                if (!islo) s = -s;
                if (!dorot) { c = 1.0f; s = 0.0f; tsgn = 0.0f; }
                nown = fmaf(tsgn, d, nown);
                #pragma unroll
                for (int e = 0; e < DD; ++e)
                    w[e] = fmaf(-s, oth[e], c * w[e]);
            }
        }
        if (!sweep_rotated) break;   // identity sweep -> all later identity
    }

    // Stash W (column per lane) into d_out; epilogue kernel transforms in place.
    float* Wb = Wout + (size_t)b * DD * DD;
    #pragma unroll
    for (int e = 0; e < DD; ++e)
        Wb[e * DD + lane] = w[e];    // coalesced
}

// ---------------- Kernel 2: epilogue out = W diag(scl) W^T (in place) --------
// One 256-thread block per matrix; W staged fully into LDS before any write,
// so the in-place overwrite of d_out is race-free (block-local).
__global__ __launch_bounds__(256, 2)
void logeig_epilogue_kernel(float* __restrict__ out, int nb) {
    __shared__ float M[DD][DD + 1];
    __shared__ float sc[DD];

    const int b = blockIdx.x;
    if (b >= nb) return;
    const int tid  = threadIdx.x;
    const int lane = tid & 63;
    const int w4   = tid >> 6;
    float* Ob = out + (size_t)b * DD * DD;

    #pragma unroll
    for (int ii = 0; ii < 16; ++ii) {
        int r = w4 * 16 + ii;
        M[r][lane] = Ob[r * DD + lane];
    }
    __syncthreads();

    if (tid < DD) {
        float n0 = 0.f, n1 = 0.f;
        #pragma unroll
        for (int e = 0; e < DD; e += 2) {
            n0 = fmaf(M[e][tid],     M[e][tid],     n0);
            n1 = fmaf(M[e + 1][tid], M[e + 1][tid], n1);
        }
        const float nn = n0 + n1;                    // lambda_j
        sc[tid] = logf(fmaxf(nn, 1e-7f)) / nn;       // log(clip(lam))/lam
    }
    __syncthreads();

    float vrow[DD];
    #pragma unroll
    for (int j = 0; j < DD; ++j) vrow[j] = M[lane][j] * sc[j];

    float acc[16];
    #pragma unroll
    for (int ii = 0; ii < 16; ++ii) acc[ii] = 0.0f;

    for (int k = 0; k < DD; ++k) {
        const float vl = vrow[k];
        #pragma unroll
        for (int ii = 0; ii < 16; ++ii)
            acc[ii] = fmaf(M[w4 * 16 + ii][k], vl, acc[ii]);   // broadcast reads
    }

    __syncthreads();   // all reads of W done before overwriting
    #pragma unroll
    for (int ii = 0; ii < 16; ++ii)
        Ob[(size_t)(w4 * 16 + ii) * DD + lane] = acc[ii];
}

extern "C" void kernel_launch(void* const* d_in, const int* in_sizes, int n_in,
                              void* d_out, int out_size, void* d_ws, size_t ws_size,
                              hipStream_t stream) {
    (void)n_in; (void)d_ws; (void)ws_size; (void)out_size;
    const float* X = (const float*)d_in[0];
    float* out = (float*)d_out;
    int nb = in_sizes[0] / (DD * DD);
    hipLaunchKernelGGL(logeig_sweeps_kernel, dim3(nb), dim3(DD), 0, stream, X, out, nb);
    hipLaunchKernelGGL(logeig_epilogue_kernel, dim3(nb), dim3(256), 0, stream, out, nb);
}

// Round 13
// 24622.517 us; speedup vs baseline: 1.5227x; 1.5227x over previous
//
#include <hip/hip_runtime.h>
#include <math.h>

#define DD 64
#define NSWEEP 8

__device__ __forceinline__ float rdlane(float v, int l) {
    return __int_as_float(__builtin_amdgcn_readlane(__float_as_int(v), l));
}
__device__ __forceinline__ float bperm(int paddr, float v) {
    return __int_as_float(__builtin_amdgcn_ds_bpermute(paddr, __float_as_int(v)));
}

// ---------------- Kernel 1: Cholesky + one-sided Jacobi sweeps ----------------
// 64-thread blocks, ZERO LDS, no asm pin (round-11: pin => scratch spill).
// launch_bounds(64,4): VGPR cap = exactly 128 (occupancy brackets step at
// 64/128/256 — round-12 lesson: asking for 5 waves/SIMD forces the <=64
// bracket and catastrophic spill). Natural VGPR 80-84 fits the <=128 bracket
// -> 4 waves/SIMD = 16 waves/CU, scratch-free.
__global__ __launch_bounds__(64, 4)
void logeig_sweeps_kernel(const float* __restrict__ X, float* __restrict__ Wout, int nb) {
    const int b = blockIdx.x;
    if (b >= nb) return;
    const int lane = threadIdx.x & 63;
    const float* Xb = X + (size_t)b * DD * DD;

    // Symmetrize directly from global: coalesced column + row (L1/L2-served).
    float w[DD];
    #pragma unroll
    for (int e = 0; e < DD; ++e)
        w[e] = 0.5f * (Xb[e * DD + lane] + Xb[lane * DD + e]);

    // ---- In-wave right-looking Cholesky: lane j ends owning column j of L ----
    #pragma unroll
    for (int k = 0; k < DD; ++k) {
        const float pivot = rdlane(w[k], k);          // A'[k][k] > 0 (SPD)
        const float rinv  = 1.0f / sqrtf(pivot);
        const float ljk   = w[k] * rinv;              // L[lane][k], valid lane >= k
        const bool  gtk   = (lane > k);
        const bool  eqk   = (lane == k);
        #pragma unroll
        for (int e = k; e < DD; ++e) {
            const float lek = rdlane(w[e], k) * rinv; // L[e][k] (uniform)
            const float upd = fmaf(-lek, ljk, w[e]);
            w[e] = eqk ? lek : (gtk ? upd : w[e]);
        }
    }
    #pragma unroll
    for (int e = 0; e < DD - 1; ++e)
        w[e] = (e < lane) ? 0.0f : w[e];

    // Initial column norm^2 (maintained incrementally)
    float nown;
    {
        float n0 = 0.f, n1 = 0.f;
        #pragma unroll
        for (int e = 0; e < DD; e += 2) {
            n0 = fmaf(w[e],     w[e],     n0);
            n1 = fmaf(w[e + 1], w[e + 1], n1);
        }
        nown = n0 + n1;
    }

    const int lane4 = lane << 2;

    for (int sw = 0; sw < NSWEEP; ++sw) {
        bool sweep_rotated = false;
        for (int m = 1; m < DD; ++m) {
            const int paddr = lane4 ^ (m << 2);   // partner*4 (XOR pairing)

            float oth[DD];
            #pragma unroll
            for (int e = 0; e < DD; ++e) oth[e] = bperm(paddr, w[e]);

            // d = w . oth (identical summation order both lanes -> bitwise-equal)
            float d0 = 0.f, d1 = 0.f, d2 = 0.f, d3 = 0.f;
            #pragma unroll
            for (int e = 0; e < DD; e += 4) {
                d0 = fmaf(w[e],     oth[e],     d0);
                d1 = fmaf(w[e + 1], oth[e + 1], d1);
                d2 = fmaf(w[e + 2], oth[e + 2], d2);
                d3 = fmaf(w[e + 3], oth[e + 3], d3);
            }
            const float d    = (d0 + d1) + (d2 + d3);
            const float noth = bperm(paddr, nown);

            // Relative threshold 1e-5 (absmax-neutral, rounds 9-12):
            // late sweeps become all-skip so the early exit fires.
            const bool dorot = (d * d > 1e-10f * nown * noth);
            if (__any(dorot)) {
                sweep_rotated = true;
                const bool  islo = (paddr > lane4);   // low lane plays p
                const float app  = islo ? nown : noth;
                const float aqq  = islo ? noth : nown;
                float tau = (aqq - app) * 0.5f / d;
                float t   = 1.0f / (fabsf(tau) + sqrtf(fmaf(tau, tau, 1.0f)));
                t = copysignf(t, tau);
                float c = 1.0f / sqrtf(fmaf(t, t, 1.0f));
                float s = t * c;
                float tsgn = islo ? -t : t;           // nown' = nown -+ t*d
                if (!islo) s = -s;
                if (!dorot) { c = 1.0f; s = 0.0f; tsgn = 0.0f; }
                nown = fmaf(tsgn, d, nown);
                #pragma unroll
                for (int e = 0; e < DD; ++e)
                    w[e] = fmaf(-s, oth[e], c * w[e]);
            }
        }
        if (!sweep_rotated) break;   // identity sweep -> all later identity
    }

    // Stash W (column per lane) into d_out; epilogue kernel transforms in place.
    float* Wb = Wout + (size_t)b * DD * DD;
    #pragma unroll
    for (int e = 0; e < DD; ++e)
        Wb[e * DD + lane] = w[e];    // coalesced
}

// ---------------- Kernel 2: epilogue out = W diag(scl) W^T (in place) --------
// One 256-thread block per matrix; W staged fully into LDS before any write,
// so the in-place overwrite of d_out is race-free (block-local).
__global__ __launch_bounds__(256, 2)
void logeig_epilogue_kernel(float* __restrict__ out, int nb) {
    __shared__ float M[DD][DD + 1];
    __shared__ float sc[DD];

    const int b = blockIdx.x;
    if (b >= nb) return;
    const int tid  = threadIdx.x;
    const int lane = tid & 63;
    const int w4   = tid >> 6;
    float* Ob = out + (size_t)b * DD * DD;

    #pragma unroll
    for (int ii = 0; ii < 16; ++ii) {
        int r = w4 * 16 + ii;
        M[r][lane] = Ob[r * DD + lane];
    }
    __syncthreads();

    if (tid < DD) {
        float n0 = 0.f, n1 = 0.f;
        #pragma unroll
        for (int e = 0; e < DD; e += 2) {
            n0 = fmaf(M[e][tid],     M[e][tid],     n0);
            n1 = fmaf(M[e + 1][tid], M[e + 1][tid], n1);
        }
        const float nn = n0 + n1;                    // lambda_j
        sc[tid] = logf(fmaxf(nn, 1e-7f)) / nn;       // log(clip(lam))/lam
    }
    __syncthreads();

    float vrow[DD];
    #pragma unroll
    for (int j = 0; j < DD; ++j) vrow[j] = M[lane][j] * sc[j];

    float acc[16];
    #pragma unroll
    for (int ii = 0; ii < 16; ++ii) acc[ii] = 0.0f;

    for (int k = 0; k < DD; ++k) {
        const float vl = vrow[k];
        #pragma unroll
        for (int ii = 0; ii < 16; ++ii)
            acc[ii] = fmaf(M[w4 * 16 + ii][k], vl, acc[ii]);   // broadcast reads
    }

    __syncthreads();   // all reads of W done before overwriting
    #pragma unroll
    for (int ii = 0; ii < 16; ++ii)
        Ob[(size_t)(w4 * 16 + ii) * DD + lane] = acc[ii];
}

extern "C" void kernel_launch(void* const* d_in, const int* in_sizes, int n_in,
                              void* d_out, int out_size, void* d_ws, size_t ws_size,
                              hipStream_t stream) {
    (void)n_in; (void)d_ws; (void)ws_size; (void)out_size;
    const float* X = (const float*)d_in[0];
    float* out = (float*)d_out;
    int nb = in_sizes[0] / (DD * DD);
    hipLaunchKernelGGL(logeig_sweeps_kernel, dim3(nb), dim3(DD), 0, stream, X, out, nb);
    hipLaunchKernelGGL(logeig_epilogue_kernel, dim3(nb), dim3(256), 0, stream, out, nb);
}

// Round 14
// 5741.540 us; speedup vs baseline: 6.5300x; 4.2885x over previous
//
#include <hip/hip_runtime.h>
#include <math.h>

#define DD 64
#define NSWEEP 8

__device__ __forceinline__ float rdlane(float v, int l) {
    return __int_as_float(__builtin_amdgcn_readlane(__float_as_int(v), l));
}
__device__ __forceinline__ float bperm(int paddr, float v) {
    return __int_as_float(__builtin_amdgcn_ds_bpermute(paddr, __float_as_int(v)));
}

// ---------------- Kernel 1: Cholesky + one-sided Jacobi sweeps ----------------
// 64-thread blocks, ZERO LDS, no asm pin.
// Empirical launch_bounds law on this backend (rounds 9-13):
//   VGPR cap = 256 / w   for __launch_bounds__(B, w)
//   (256,4)->64  (256,2)->128  (64,3)->84  (64,4)->64  (64,5)->48
// This kernel needs ~80-96 VGPR -> the ONLY non-spilling bracket is w=2
// (cap 128). HW then schedules 4 waves/SIMD (occupancy halves above 64
// VGPR) = 16 waves/CU, with no LDS and no scratch to cap it below that.
__global__ __launch_bounds__(64, 2)
void logeig_sweeps_kernel(const float* __restrict__ X, float* __restrict__ Wout, int nb) {
    const int b = blockIdx.x;
    if (b >= nb) return;
    const int lane = threadIdx.x & 63;
    const float* Xb = X + (size_t)b * DD * DD;

    // Symmetrize directly from global: coalesced column + row (L1/L2-served).
    float w[DD];
    #pragma unroll
    for (int e = 0; e < DD; ++e)
        w[e] = 0.5f * (Xb[e * DD + lane] + Xb[lane * DD + e]);

    // ---- In-wave right-looking Cholesky: lane j ends owning column j of L ----
    #pragma unroll
    for (int k = 0; k < DD; ++k) {
        const float pivot = rdlane(w[k], k);          // A'[k][k] > 0 (SPD)
        const float rinv  = 1.0f / sqrtf(pivot);
        const float ljk   = w[k] * rinv;              // L[lane][k], valid lane >= k
        const bool  gtk   = (lane > k);
        const bool  eqk   = (lane == k);
        #pragma unroll
        for (int e = k; e < DD; ++e) {
            const float lek = rdlane(w[e], k) * rinv; // L[e][k] (uniform)
            const float upd = fmaf(-lek, ljk, w[e]);
            w[e] = eqk ? lek : (gtk ? upd : w[e]);
        }
    }
    #pragma unroll
    for (int e = 0; e < DD - 1; ++e)
        w[e] = (e < lane) ? 0.0f : w[e];

    // Initial column norm^2 (maintained incrementally)
    float nown;
    {
        float n0 = 0.f, n1 = 0.f;
        #pragma unroll
        for (int e = 0; e < DD; e += 2) {
            n0 = fmaf(w[e],     w[e],     n0);
            n1 = fmaf(w[e + 1], w[e + 1], n1);
        }
        nown = n0 + n1;
    }

    const int lane4 = lane << 2;

    for (int sw = 0; sw < NSWEEP; ++sw) {
        bool sweep_rotated = false;
        for (int m = 1; m < DD; ++m) {
            const int paddr = lane4 ^ (m << 2);   // partner*4 (XOR pairing)

            float oth[DD];
            #pragma unroll
            for (int e = 0; e < DD; ++e) oth[e] = bperm(paddr, w[e]);

            // d = w . oth (identical summation order both lanes -> bitwise-equal)
            float d0 = 0.f, d1 = 0.f, d2 = 0.f, d3 = 0.f;
            #pragma unroll
            for (int e = 0; e < DD; e += 4) {
                d0 = fmaf(w[e],     oth[e],     d0);
                d1 = fmaf(w[e + 1], oth[e + 1], d1);
                d2 = fmaf(w[e + 2], oth[e + 2], d2);
                d3 = fmaf(w[e + 3], oth[e + 3], d3);
            }
            const float d    = (d0 + d1) + (d2 + d3);
            const float noth = bperm(paddr, nown);

            // Relative threshold 1e-5 (absmax-neutral, rounds 9-13):
            // late sweeps become all-skip so the early exit fires.
            const bool dorot = (d * d > 1e-10f * nown * noth);
            if (__any(dorot)) {
                sweep_rotated = true;
                const bool  islo = (paddr > lane4);   // low lane plays p
                const float app  = islo ? nown : noth;
                const float aqq  = islo ? noth : nown;
                float tau = (aqq - app) * 0.5f / d;
                float t   = 1.0f / (fabsf(tau) + sqrtf(fmaf(tau, tau, 1.0f)));
                t = copysignf(t, tau);
                float c = 1.0f / sqrtf(fmaf(t, t, 1.0f));
                float s = t * c;
                float tsgn = islo ? -t : t;           // nown' = nown -+ t*d
                if (!islo) s = -s;
                if (!dorot) { c = 1.0f; s = 0.0f; tsgn = 0.0f; }
                nown = fmaf(tsgn, d, nown);
                #pragma unroll
                for (int e = 0; e < DD; ++e)
                    w[e] = fmaf(-s, oth[e], c * w[e]);
            }
        }
        if (!sweep_rotated) break;   // identity sweep -> all later identity
    }

    // Stash W (column per lane) into d_out; epilogue kernel transforms in place.
    float* Wb = Wout + (size_t)b * DD * DD;
    #pragma unroll
    for (int e = 0; e < DD; ++e)
        Wb[e * DD + lane] = w[e];    // coalesced
}

// ---------------- Kernel 2: epilogue out = W diag(scl) W^T (in place) --------
// One 256-thread block per matrix; W staged fully into LDS before any write,
// so the in-place overwrite of d_out is race-free (block-local).
__global__ __launch_bounds__(256, 2)
void logeig_epilogue_kernel(float* __restrict__ out, int nb) {
    __shared__ float M[DD][DD + 1];
    __shared__ float sc[DD];

    const int b = blockIdx.x;
    if (b >= nb) return;
    const int tid  = threadIdx.x;
    const int lane = tid & 63;
    const int w4   = tid >> 6;
    float* Ob = out + (size_t)b * DD * DD;

    #pragma unroll
    for (int ii = 0; ii < 16; ++ii) {
        int r = w4 * 16 + ii;
        M[r][lane] = Ob[r * DD + lane];
    }
    __syncthreads();

    if (tid < DD) {
        float n0 = 0.f, n1 = 0.f;
        #pragma unroll
        for (int e = 0; e < DD; e += 2) {
            n0 = fmaf(M[e][tid],     M[e][tid],     n0);
            n1 = fmaf(M[e + 1][tid], M[e + 1][tid], n1);
        }
        const float nn = n0 + n1;                    // lambda_j
        sc[tid] = logf(fmaxf(nn, 1e-7f)) / nn;       // log(clip(lam))/lam
    }
    __syncthreads();

    float vrow[DD];
    #pragma unroll
    for (int j = 0; j < DD; ++j) vrow[j] = M[lane][j] * sc[j];

    float acc[16];
    #pragma unroll
    for (int ii = 0; ii < 16; ++ii) acc[ii] = 0.0f;

    for (int k = 0; k < DD; ++k) {
        const float vl = vrow[k];
        #pragma unroll
        for (int ii = 0; ii < 16; ++ii)
            acc[ii] = fmaf(M[w4 * 16 + ii][k], vl, acc[ii]);   // broadcast reads
    }

    __syncthreads();   // all reads of W done before overwriting
    #pragma unroll
    for (int ii = 0; ii < 16; ++ii)
        Ob[(size_t)(w4 * 16 + ii) * DD + lane] = acc[ii];
}

extern "C" void kernel_launch(void* const* d_in, const int* in_sizes, int n_in,
                              void* d_out, int out_size, void* d_ws, size_t ws_size,
                              hipStream_t stream) {
    (void)n_in; (void)d_ws; (void)ws_size; (void)out_size;
    const float* X = (const float*)d_in[0];
    float* out = (float*)d_out;
    int nb = in_sizes[0] / (DD * DD);
    hipLaunchKernelGGL(logeig_sweeps_kernel, dim3(nb), dim3(DD), 0, stream, X, out, nb);
    hipLaunchKernelGGL(logeig_epilogue_kernel, dim3(nb), dim3(256), 0, stream, out, nb);
}

// Round 15
// 5541.077 us; speedup vs baseline: 6.7662x; 1.0362x over previous
//
#include <hip/hip_runtime.h>
#include <math.h>

#define DD 64
#define NSWEEP 8

typedef float f32x2 __attribute__((ext_vector_type(2)));

__device__ __forceinline__ float rdlane(float v, int l) {
    return __int_as_float(__builtin_amdgcn_readlane(__float_as_int(v), l));
}
__device__ __forceinline__ float bperm(int paddr, float v) {
    return __int_as_float(__builtin_amdgcn_ds_bpermute(paddr, __float_as_int(v)));
}

// ---------------- Kernel 1: Cholesky + one-sided Jacobi sweeps ----------------
// 64-thread blocks, ZERO LDS, no pin, launch_bounds(64,2) (VGPR cap 128 — the
// only non-spilling bracket; effective pool ~256 VGPR/SIMD: 128->2 waves/SIMD).
// Round-14 lesson: duration is INSENSITIVE to occupancy (22-33% all ~6ms) and
// VALUBusy=63% -> VALU-issue bound. This round: packed f32 (v_pk_fma_f32 via
// <2 x float> IR) halves rotation+dot issue count; branchless rotation lets
// the scheduler overlap next-stage bpermutes with the rotation tail.
__global__ __launch_bounds__(64, 2)
void logeig_sweeps_kernel(const float* __restrict__ X, float* __restrict__ Wout, int nb) {
    const int b = blockIdx.x;
    if (b >= nb) return;
    const int lane = threadIdx.x & 63;
    const float* Xb = X + (size_t)b * DD * DD;

    // Symmetrize directly from global, packed 2 elems/reg-pair.
    f32x2 w2[DD / 2];
    #pragma unroll
    for (int i = 0; i < DD / 2; ++i) {
        const int e0 = 2 * i, e1 = 2 * i + 1;
        w2[i].x = 0.5f * (Xb[e0 * DD + lane] + Xb[lane * DD + e0]);
        w2[i].y = 0.5f * (Xb[e1 * DD + lane] + Xb[lane * DD + e1]);
    }

    // ---- In-wave right-looking Cholesky: lane j ends owning column j of L ----
    // (scalar element access, compile-time indices; one-time ~1 stage of cost)
    #pragma unroll
    for (int k = 0; k < DD; ++k) {
        const float pivot = rdlane(w2[k >> 1][k & 1], k);
        const float rinv  = 1.0f / sqrtf(pivot);
        const float ljk   = w2[k >> 1][k & 1] * rinv;
        const bool  gtk   = (lane > k);
        const bool  eqk   = (lane == k);
        #pragma unroll
        for (int e = k; e < DD; ++e) {
            const float we  = w2[e >> 1][e & 1];
            const float lek = rdlane(we, k) * rinv;
            const float upd = fmaf(-lek, ljk, we);
            w2[e >> 1][e & 1] = eqk ? lek : (gtk ? upd : we);
        }
    }
    #pragma unroll
    for (int e = 0; e < DD - 1; ++e)
        if (e < lane) w2[e >> 1][e & 1] = 0.0f;

    // Initial column norm^2 (maintained incrementally); packed accumulate.
    float nown;
    {
        f32x2 nv0 = {0.f, 0.f}, nv1 = {0.f, 0.f};
        #pragma unroll
        for (int i = 0; i < DD / 2; i += 2) {
            nv0 = w2[i] * w2[i] + nv0;
            nv1 = w2[i + 1] * w2[i + 1] + nv1;
        }
        nown = (nv0.x + nv0.y) + (nv1.x + nv1.y);
    }

    const int lane4 = lane << 2;

    for (int sw = 0; sw < NSWEEP; ++sw) {
        bool sweep_rotated = false;
        for (int m = 1; m < DD; ++m) {
            const int paddr = lane4 ^ (m << 2);   // partner*4 (XOR pairing)

            f32x2 oth2[DD / 2];
            #pragma unroll
            for (int i = 0; i < DD / 2; ++i) {
                oth2[i].x = bperm(paddr, w2[i].x);
                oth2[i].y = bperm(paddr, w2[i].y);
            }

            // d = w . oth, packed (identical expression both lanes of a pair;
            // elementwise products commute bitwise -> d bitwise-equal).
            f32x2 dv0 = {0.f, 0.f}, dv1 = {0.f, 0.f};
            #pragma unroll
            for (int i = 0; i < DD / 2; i += 2) {
                dv0 = w2[i] * oth2[i] + dv0;
                dv1 = w2[i + 1] * oth2[i + 1] + dv1;
            }
            const float d    = (dv0.x + dv0.y) + (dv1.x + dv1.y);
            const float noth = bperm(paddr, nown);

            // Relative threshold 1e-5 (absmax-neutral, rounds 9-14).
            const bool dorot = (d * d > 1e-10f * nown * noth);
            sweep_rotated = sweep_rotated || __any(dorot);

            // Branchless rotation: per-lane identity fallback when !dorot.
            const bool  islo = (paddr > lane4);   // low lane plays p
            const float app  = islo ? nown : noth;
            const float aqq  = islo ? noth : nown;
            float tau = (aqq - app) * 0.5f / d;
            float t   = 1.0f / (fabsf(tau) + sqrtf(fmaf(tau, tau, 1.0f)));
            t = copysignf(t, tau);
            float c = 1.0f / sqrtf(fmaf(t, t, 1.0f));
            float s = t * c;
            float tsgn = islo ? -t : t;           // nown' = nown -+ t*d
            if (!islo) s = -s;
            if (!dorot) { c = 1.0f; s = 0.0f; tsgn = 0.0f; }
            nown = fmaf(tsgn, d, nown);

            const f32x2 c2 = {c, c};
            const f32x2 s2 = {s, s};
            #pragma unroll
            for (int i = 0; i < DD / 2; ++i)
                w2[i] = c2 * w2[i] - s2 * oth2[i];   // pk_mul + pk_fma
        }
        if (!sweep_rotated) break;   // identity sweep -> all later identity
    }

    // Stash W (column per lane) into d_out; epilogue kernel transforms in place.
    float* Wb = Wout + (size_t)b * DD * DD;
    #pragma unroll
    for (int e = 0; e < DD; ++e)
        Wb[e * DD + lane] = w2[e >> 1][e & 1];   // coalesced
}

// ---------------- Kernel 2: epilogue out = W diag(scl) W^T (in place) --------
// One 256-thread block per matrix; W staged fully into LDS before any write,
// so the in-place overwrite of d_out is race-free (block-local).
__global__ __launch_bounds__(256, 2)
void logeig_epilogue_kernel(float* __restrict__ out, int nb) {
    __shared__ float M[DD][DD + 1];
    __shared__ float sc[DD];

    const int b = blockIdx.x;
    if (b >= nb) return;
    const int tid  = threadIdx.x;
    const int lane = tid & 63;
    const int w4   = tid >> 6;
    float* Ob = out + (size_t)b * DD * DD;

    #pragma unroll
    for (int ii = 0; ii < 16; ++ii) {
        int r = w4 * 16 + ii;
        M[r][lane] = Ob[r * DD + lane];
    }
    __syncthreads();

    if (tid < DD) {
        float n0 = 0.f, n1 = 0.f;
        #pragma unroll
        for (int e = 0; e < DD; e += 2) {
            n0 = fmaf(M[e][tid],     M[e][tid],     n0);
            n1 = fmaf(M[e + 1][tid], M[e + 1][tid], n1);
        }
        const float nn = n0 + n1;                    // lambda_j
        sc[tid] = logf(fmaxf(nn, 1e-7f)) / nn;       // log(clip(lam))/lam
    }
    __syncthreads();

    float vrow[DD];
    #pragma unroll
    for (int j = 0; j < DD; ++j) vrow[j] = M[lane][j] * sc[j];

    float acc[16];
    #pragma unroll
    for (int ii = 0; ii < 16; ++ii) acc[ii] = 0.0f;

    for (int k = 0; k < DD; ++k) {
        const float vl = vrow[k];
        #pragma unroll
        for (int ii = 0; ii < 16; ++ii)
            acc[ii] = fmaf(M[w4 * 16 + ii][k], vl, acc[ii]);   // broadcast reads
    }

    __syncthreads();   // all reads of W done before overwriting
    #pragma unroll
    for (int ii = 0; ii < 16; ++ii)
        Ob[(size_t)(w4 * 16 + ii) * DD + lane] = acc[ii];
}

extern "C" void kernel_launch(void* const* d_in, const int* in_sizes, int n_in,
                              void* d_out, int out_size, void* d_ws, size_t ws_size,
                              hipStream_t stream) {
    (void)n_in; (void)d_ws; (void)ws_size; (void)out_size;
    const float* X = (const float*)d_in[0];
    float* out = (float*)d_out;
    int nb = in_sizes[0] / (DD * DD);
    hipLaunchKernelGGL(logeig_sweeps_kernel, dim3(nb), dim3(DD), 0, stream, X, out, nb);
    hipLaunchKernelGGL(logeig_epilogue_kernel, dim3(nb), dim3(256), 0, stream, out, nb);
}